// Round 3
// baseline (791.486 us; speedup 1.0000x reference)
//
#include <hip/hip_runtime.h>
#include <math.h>

#define NN 100000
#define NE 1600000
#define INF_ 128
#define HID 64
#define NEG 0.2f
#define NBLK1 98   // ceil(NN/1024) for scan

__device__ __forceinline__ float lrelu(float v){ return v > 0.f ? v : NEG*v; }

// ---------------- CSR build ----------------

__global__ void k_zero_i(int* p, int n){
  int i = blockIdx.x*blockDim.x + threadIdx.x;
  if (i < n) p[i] = 0;
}

__global__ void k_count(const int* __restrict__ dst, int* __restrict__ cnt){
  int e = blockIdx.x*blockDim.x + threadIdx.x;
  if (e < NE) atomicAdd(&cnt[dst[e]], 1);
}

__global__ void k_dinv(const int* __restrict__ cnt, float* __restrict__ dinv){
  int i = blockIdx.x*blockDim.x + threadIdx.x;
  if (i < NN) dinv[i] = rsqrtf((float)cnt[i] + 1.0f);
}

// block-level scan: 256 threads x 4 elements; exclusive offsets + block partial
__global__ __launch_bounds__(256) void k_scan1(const int* __restrict__ cnt,
                                               int* __restrict__ off,
                                               int* __restrict__ part){
  __shared__ int l[256];
  int t = threadIdx.x;
  int base = blockIdx.x*1024 + t*4;
  int a0 = (base+0 < NN) ? cnt[base+0] : 0;
  int a1 = (base+1 < NN) ? cnt[base+1] : 0;
  int a2 = (base+2 < NN) ? cnt[base+2] : 0;
  int a3 = (base+3 < NN) ? cnt[base+3] : 0;
  int s = a0+a1+a2+a3;
  l[t] = s; __syncthreads();
  for (int o = 1; o < 256; o <<= 1){
    int v = (t >= o) ? l[t-o] : 0;
    __syncthreads();
    l[t] += v;
    __syncthreads();
  }
  if (t == 255) part[blockIdx.x] = l[255];
  int e0 = l[t] - s;   // exclusive within block
  if (base+0 < NN) off[base+0] = e0;
  if (base+1 < NN) off[base+1] = e0 + a0;
  if (base+2 < NN) off[base+2] = e0 + a0 + a1;
  if (base+3 < NN) off[base+3] = e0 + a0 + a1 + a2;
}

__global__ __launch_bounds__(128) void k_scan2(int* part){
  __shared__ int l[128];
  int t = threadIdx.x;
  int v = (t < NBLK1) ? part[t] : 0;
  l[t] = v; __syncthreads();
  for (int o = 1; o < 128; o <<= 1){
    int u = (t >= o) ? l[t-o] : 0;
    __syncthreads();
    l[t] += u;
    __syncthreads();
  }
  if (t < NBLK1) part[t] = l[t] - v;   // exclusive block offsets
}

__global__ void k_scan3(int* off, const int* __restrict__ part){
  int i = blockIdx.x*blockDim.x + threadIdx.x;
  if (i < NN) off[i] += part[i >> 10];
  if (i == 0) off[NN] = NE;
}

__global__ void k_fill(const int* __restrict__ src, const int* __restrict__ dst,
                       const int* __restrict__ off, int* cur, int* __restrict__ csr){
  int e = blockIdx.x*blockDim.x + threadIdx.x;
  if (e < NE){
    int d = dst[e];
    int p = atomicAdd(&cur[d], 1);
    csr[off[d] + p] = src[e];
  }
}

// ---------------- dense linears ----------------

// hs[N,64] = (x[N,128] @ w[128,64]) * dinv[row]   (GCN src pre-scaling fused)
__global__ __launch_bounds__(256) void k_gemm_in(const float* __restrict__ x,
                                                 const float* __restrict__ w,
                                                 const float* __restrict__ dinv,
                                                 float* __restrict__ hs){
  __shared__ float wl[INF_*HID];
  for (int i = threadIdx.x; i < INF_*HID; i += 256) wl[i] = w[i];
  __syncthreads();
  const int wave = threadIdx.x >> 6, lane = threadIdx.x & 63;
  for (int row = blockIdx.x*4 + wave; row < NN; row += gridDim.x*4){
    float xv0 = x[(size_t)row*INF_ + lane];
    float xv1 = x[(size_t)row*INF_ + 64 + lane];
    float acc = 0.f;
    #pragma unroll
    for (int k = 0; k < 64; ++k) acc += __shfl(xv0, k, 64)*wl[k*HID + lane];
    #pragma unroll
    for (int k = 0; k < 64; ++k) acc += __shfl(xv1, k, 64)*wl[(64+k)*HID + lane];
    hs[(size_t)row*HID + lane] = acc*dinv[row];
  }
}

// h2pre = h1 @ gat_w; as_ = h2pre.att_src; ad_ = h2pre.att_dst
__global__ __launch_bounds__(256) void k_gat_lin(const float* __restrict__ h1,
                                                 const float* __restrict__ w,
                                                 const float* __restrict__ atts,
                                                 const float* __restrict__ attd,
                                                 float* __restrict__ h2pre,
                                                 float* __restrict__ as_,
                                                 float* __restrict__ ad_){
  __shared__ float wl[HID*HID];
  __shared__ float asl[HID], adl[HID];
  for (int i = threadIdx.x; i < HID*HID; i += 256) wl[i] = w[i];
  if (threadIdx.x < HID){
    asl[threadIdx.x] = atts[threadIdx.x];
    adl[threadIdx.x] = attd[threadIdx.x];
  }
  __syncthreads();
  const int wave = threadIdx.x >> 6, lane = threadIdx.x & 63;
  for (int row = blockIdx.x*4 + wave; row < NN; row += gridDim.x*4){
    float hv = h1[(size_t)row*HID + lane];
    float acc = 0.f;
    #pragma unroll
    for (int k = 0; k < HID; ++k) acc += __shfl(hv, k, 64)*wl[k*HID + lane];
    h2pre[(size_t)row*HID + lane] = acc;
    float vs = acc*asl[lane], vd = acc*adl[lane];
    #pragma unroll
    for (int o = 32; o > 0; o >>= 1){
      vs += __shfl_xor(vs, o, 64);
      vd += __shfl_xor(vd, o, 64);
    }
    if (lane == 0){ as_[row] = vs; ad_[row] = vd; }
  }
}

// ---------------- gather aggregations: 4-row-slot x float4 ----------------
// lane = (q = lane>>4 row slot, f = lane&15 feature quad). Each slot reads
// whole 256B rows as float4; 4 rows (8 w/ unroll) in flight per wave.

// GCN: h1 = relu((sum_s hs[s] + hs[i]) * dinv[i] + gcn_b)
__global__ __launch_bounds__(256) void k_gcn_gather(const int* __restrict__ csr,
                                                    const int* __restrict__ off,
                                                    const float4* __restrict__ hs4,
                                                    const float* __restrict__ dinv,
                                                    const float4* __restrict__ gcn_b4,
                                                    float4* __restrict__ h1_4){
  int node = blockIdx.x*4 + (threadIdx.x >> 6);
  if (node >= NN) return;
  int lane = threadIdx.x & 63;
  int q = lane >> 4, f = lane & 15;
  int beg = off[node], end = off[node+1];
  float4 acc = {0.f,0.f,0.f,0.f};
  for (int c = beg; c < end; c += 64){
    int n = end - c; if (n > 64) n = 64;
    int idx = (lane < n) ? csr[c + lane] : 0;
    for (int k = 0; k < n; k += 8){
      int e0 = k + q, e1 = k + 4 + q;
      int s0 = __shfl(idx, e0, 64);
      int s1 = __shfl(idx, e1, 64);
      if (e0 < n){
        float4 r = hs4[(size_t)s0*16 + f];
        acc.x += r.x; acc.y += r.y; acc.z += r.z; acc.w += r.w;
      }
      if (e1 < n){
        float4 r = hs4[(size_t)s1*16 + f];
        acc.x += r.x; acc.y += r.y; acc.z += r.z; acc.w += r.w;
      }
    }
  }
  #pragma unroll
  for (int o = 16; o <= 32; o <<= 1){
    acc.x += __shfl_xor(acc.x, o, 64);
    acc.y += __shfl_xor(acc.y, o, 64);
    acc.z += __shfl_xor(acc.z, o, 64);
    acc.w += __shfl_xor(acc.w, o, 64);
  }
  if (q == 0){
    float4 s  = hs4[(size_t)node*16 + f];
    float  di = dinv[node];
    float4 b4 = gcn_b4[f];
    float4 o;
    o.x = fmaxf((acc.x + s.x)*di + b4.x, 0.f);
    o.y = fmaxf((acc.y + s.y)*di + b4.y, 0.f);
    o.z = fmaxf((acc.z + s.z)*di + b4.z, 0.f);
    o.w = fmaxf((acc.w + s.w)*di + b4.w, 0.f);
    h1_4[(size_t)node*16 + f] = o;
  }
}

// GAT: fused segment softmax + weighted gather
__global__ __launch_bounds__(256) void k_gat_gather(const int* __restrict__ csr,
                                                    const int* __restrict__ off,
                                                    const float* __restrict__ as_,
                                                    const float* __restrict__ ad_,
                                                    const float4* __restrict__ h2pre4,
                                                    const float4* __restrict__ gat_b4,
                                                    float4* __restrict__ h2_4){
  int node = blockIdx.x*4 + (threadIdx.x >> 6);
  if (node >= NN) return;
  int lane = threadIdx.x & 63;
  int q = lane >> 4, f = lane & 15;
  int beg = off[node], end = off[node+1];
  float adi = ad_[node];
  float eself = lrelu(as_[node] + adi);
  // pass 1: max over incoming edges (lane-parallel)
  float lm = -1e30f;
  for (int c = beg + lane; c < end; c += 64)
    lm = fmaxf(lm, lrelu(as_[csr[c]] + adi));
  #pragma unroll
  for (int o = 32; o > 0; o >>= 1) lm = fmaxf(lm, __shfl_xor(lm, o, 64));
  float m = fmaxf(eself, lm);
  float ps = expf(eself - m);
  // pass 2: p-sum and weighted row accumulation
  float ssum = 0.f;
  float4 acc = {0.f,0.f,0.f,0.f};
  for (int c = beg; c < end; c += 64){
    int n = end - c; if (n > 64) n = 64;
    int idx = 0; float pv = 0.f;
    if (lane < n){
      idx = csr[c + lane];
      pv = expf(lrelu(as_[idx] + adi) - m);
    }
    for (int k = 0; k < n; k += 8){
      int e0 = k + q, e1 = k + 4 + q;
      int s0 = __shfl(idx, e0, 64); float p0 = __shfl(pv, e0, 64);
      int s1 = __shfl(idx, e1, 64); float p1 = __shfl(pv, e1, 64);
      if (e0 < n){
        float4 r = h2pre4[(size_t)s0*16 + f];
        acc.x += r.x*p0; acc.y += r.y*p0; acc.z += r.z*p0; acc.w += r.w*p0;
        ssum += p0;
      }
      if (e1 < n){
        float4 r = h2pre4[(size_t)s1*16 + f];
        acc.x += r.x*p1; acc.y += r.y*p1; acc.z += r.z*p1; acc.w += r.w*p1;
        ssum += p1;
      }
    }
  }
  #pragma unroll
  for (int o = 16; o <= 32; o <<= 1){
    acc.x += __shfl_xor(acc.x, o, 64);
    acc.y += __shfl_xor(acc.y, o, 64);
    acc.z += __shfl_xor(acc.z, o, 64);
    acc.w += __shfl_xor(acc.w, o, 64);
    ssum  += __shfl_xor(ssum,  o, 64);
  }
  if (q == 0){
    float inv = 1.f/(ssum + ps);
    float4 h0 = h2pre4[(size_t)node*16 + f];
    float4 b4 = gat_b4[f];
    float4 o;
    o.x = fmaxf((acc.x + h0.x*ps)*inv + b4.x, 0.f);
    o.y = fmaxf((acc.y + h0.y*ps)*inv + b4.y, 0.f);
    o.z = fmaxf((acc.z + h0.z*ps)*inv + b4.z, 0.f);
    o.w = fmaxf((acc.w + h0.w*ps)*inv + b4.w, 0.f);
    h2_4[(size_t)node*16 + f] = o;
  }
}

// SAGE gather: mean of h2 rows over incoming edges
__global__ __launch_bounds__(256) void k_sage_gather(const int* __restrict__ csr,
                                                     const int* __restrict__ off,
                                                     const int* __restrict__ cnt,
                                                     const float4* __restrict__ h2_4,
                                                     float4* __restrict__ mean4){
  int node = blockIdx.x*4 + (threadIdx.x >> 6);
  if (node >= NN) return;
  int lane = threadIdx.x & 63;
  int q = lane >> 4, f = lane & 15;
  int beg = off[node], end = off[node+1];
  float4 acc = {0.f,0.f,0.f,0.f};
  for (int c = beg; c < end; c += 64){
    int n = end - c; if (n > 64) n = 64;
    int idx = (lane < n) ? csr[c + lane] : 0;
    for (int k = 0; k < n; k += 8){
      int e0 = k + q, e1 = k + 4 + q;
      int s0 = __shfl(idx, e0, 64);
      int s1 = __shfl(idx, e1, 64);
      if (e0 < n){
        float4 r = h2_4[(size_t)s0*16 + f];
        acc.x += r.x; acc.y += r.y; acc.z += r.z; acc.w += r.w;
      }
      if (e1 < n){
        float4 r = h2_4[(size_t)s1*16 + f];
        acc.x += r.x; acc.y += r.y; acc.z += r.z; acc.w += r.w;
      }
    }
  }
  #pragma unroll
  for (int o = 16; o <= 32; o <<= 1){
    acc.x += __shfl_xor(acc.x, o, 64);
    acc.y += __shfl_xor(acc.y, o, 64);
    acc.z += __shfl_xor(acc.z, o, 64);
    acc.w += __shfl_xor(acc.w, o, 64);
  }
  if (q == 0){
    float inv = 1.f/fmaxf((float)cnt[node], 1.f);
    float4 o = {acc.x*inv, acc.y*inv, acc.z*inv, acc.w*inv};
    mean4[(size_t)node*16 + f] = o;
  }
}

// SAGE dense: out = mean@wl + h2@wr + b
// NOTE: mean/out may alias (fallback path) — per-row read->compute->write is safe.
__global__ __launch_bounds__(256) void k_sage_dense(const float* mean,
                                                    const float* __restrict__ h2,
                                                    const float* __restrict__ wlh,
                                                    const float* __restrict__ wrh,
                                                    const float* __restrict__ b,
                                                    float* out){
  __shared__ float wll[HID*HID], wrl[HID*HID], bl[HID];
  for (int i = threadIdx.x; i < HID*HID; i += 256){ wll[i] = wlh[i]; wrl[i] = wrh[i]; }
  if (threadIdx.x < HID) bl[threadIdx.x] = b[threadIdx.x];
  __syncthreads();
  const int wave = threadIdx.x >> 6, lane = threadIdx.x & 63;
  for (int row = blockIdx.x*4 + wave; row < NN; row += gridDim.x*4){
    float mv = mean[(size_t)row*HID + lane];
    float hv = h2[(size_t)row*HID + lane];
    float acc = bl[lane];
    #pragma unroll
    for (int k = 0; k < HID; ++k)
      acc += __shfl(mv, k, 64)*wll[k*HID + lane] + __shfl(hv, k, 64)*wrl[k*HID + lane];
    out[(size_t)row*HID + lane] = acc;
  }
}

// ---------------- launch ----------------

extern "C" void kernel_launch(void* const* d_in, const int* in_sizes, int n_in,
                              void* d_out, int out_size, void* d_ws, size_t ws_size,
                              hipStream_t stream) {
  const float* x      = (const float*)d_in[0];
  const int*   ei     = (const int*)d_in[1];
  const int*   src    = ei;
  const int*   dstp   = ei + NE;
  const float* gcn_w  = (const float*)d_in[2];
  const float* gcn_b  = (const float*)d_in[3];
  const float* gat_w  = (const float*)d_in[4];
  const float* att_s  = (const float*)d_in[5];
  const float* att_d  = (const float*)d_in[6];
  const float* gat_b  = (const float*)d_in[7];
  const float* s_wl   = (const float*)d_in[8];
  const float* s_wr   = (const float*)d_in[9];
  const float* s_b    = (const float*)d_in[10];
  float* outp = (float*)d_out;

  // workspace layout (4-byte words)
  int*   cnt  = (int*)d_ws;          // N
  int*   cur  = cnt + NN;            // N
  int*   off  = cur + NN;            // N+1
  int*   part = off + NN + 1;        // 1024 (pad)
  float* dinv = (float*)(part + 1024);
  float* as_  = dinv + NN;
  float* ad_  = as_  + NN;
  int*   csr  = (int*)(ad_ + NN);    // NE
  float* BIG0 = (float*)(csr + NE);  // N*HID
  float* BIG1 = BIG0 + (size_t)NN*HID;

  size_t need_full = ((size_t)5*NN + 1 + 1024 + NE + (size_t)2*NN*HID)*4;
  float *P_hs, *P_h1, *P_h2pre, *P_h2, *P_mean;
  if (ws_size >= need_full){
    P_hs = BIG0; P_h1 = BIG1; P_h2pre = outp; P_h2 = BIG1; P_mean = BIG0;
  } else {
    P_hs = outp; P_h1 = BIG0; P_h2pre = outp; P_h2 = BIG0; P_mean = outp;
  }

  const int B = 256;
  // CSR build (counting sort by dst)
  k_zero_i<<<(2*NN + B-1)/B, B, 0, stream>>>(cnt, 2*NN);
  k_count <<<(NE + B-1)/B, B, 0, stream>>>(dstp, cnt);
  k_dinv  <<<(NN + B-1)/B, B, 0, stream>>>(cnt, dinv);
  k_scan1 <<<NBLK1, B, 0, stream>>>(cnt, off, part);
  k_scan2 <<<1, 128, 0, stream>>>(part);
  k_scan3 <<<(NN + B-1)/B, B, 0, stream>>>(off, part);
  k_fill  <<<(NE + B-1)/B, B, 0, stream>>>(src, dstp, off, cur, csr);

  // GCN
  k_gemm_in   <<<2048, B, 0, stream>>>(x, gcn_w, dinv, P_hs);
  k_gcn_gather<<<(NN + 3)/4, B, 0, stream>>>(csr, off, (const float4*)P_hs, dinv,
                                             (const float4*)gcn_b, (float4*)P_h1);

  // GAT
  k_gat_lin   <<<2048, B, 0, stream>>>(P_h1, gat_w, att_s, att_d, P_h2pre, as_, ad_);
  k_gat_gather<<<(NN + 3)/4, B, 0, stream>>>(csr, off, as_, ad_, (const float4*)P_h2pre,
                                             (const float4*)gat_b, (float4*)P_h2);

  // SAGE
  k_sage_gather<<<(NN + 3)/4, B, 0, stream>>>(csr, off, cnt, (const float4*)P_h2,
                                              (float4*)P_mean);
  k_sage_dense <<<2048, B, 0, stream>>>(P_mean, P_h2, s_wl, s_wr, s_b, outp);
}

// Round 4
// 567.419 us; speedup vs baseline: 1.3949x; 1.3949x over previous
//
#include <hip/hip_runtime.h>
#include <math.h>

#define NN 100000
#define NE 1600000
#define INF_ 128
#define HID 64
#define NEG 0.2f
#define NBLK1 98   // ceil(NN/1024) for scan

__device__ __forceinline__ float lrelu(float v){ return v > 0.f ? v : NEG*v; }

// ---------------- CSR build ----------------

__global__ void k_zero_i(int* p, int n){
  int i = blockIdx.x*blockDim.x + threadIdx.x;
  if (i < n) p[i] = 0;
}

__global__ void k_count(const int* __restrict__ dst, int* __restrict__ cnt){
  int e = blockIdx.x*blockDim.x + threadIdx.x;
  if (e < NE) atomicAdd(&cnt[dst[e]], 1);
}

__global__ void k_dinv(const int* __restrict__ cnt, float* __restrict__ dinv){
  int i = blockIdx.x*blockDim.x + threadIdx.x;
  if (i < NN) dinv[i] = rsqrtf((float)cnt[i] + 1.0f);
}

__global__ __launch_bounds__(256) void k_scan1(const int* __restrict__ cnt,
                                               int* __restrict__ off,
                                               int* __restrict__ part){
  __shared__ int l[256];
  int t = threadIdx.x;
  int base = blockIdx.x*1024 + t*4;
  int a0 = (base+0 < NN) ? cnt[base+0] : 0;
  int a1 = (base+1 < NN) ? cnt[base+1] : 0;
  int a2 = (base+2 < NN) ? cnt[base+2] : 0;
  int a3 = (base+3 < NN) ? cnt[base+3] : 0;
  int s = a0+a1+a2+a3;
  l[t] = s; __syncthreads();
  for (int o = 1; o < 256; o <<= 1){
    int v = (t >= o) ? l[t-o] : 0;
    __syncthreads();
    l[t] += v;
    __syncthreads();
  }
  if (t == 255) part[blockIdx.x] = l[255];
  int e0 = l[t] - s;
  if (base+0 < NN) off[base+0] = e0;
  if (base+1 < NN) off[base+1] = e0 + a0;
  if (base+2 < NN) off[base+2] = e0 + a0 + a1;
  if (base+3 < NN) off[base+3] = e0 + a0 + a1 + a2;
}

__global__ __launch_bounds__(128) void k_scan2(int* part){
  __shared__ int l[128];
  int t = threadIdx.x;
  int v = (t < NBLK1) ? part[t] : 0;
  l[t] = v; __syncthreads();
  for (int o = 1; o < 128; o <<= 1){
    int u = (t >= o) ? l[t-o] : 0;
    __syncthreads();
    l[t] += u;
    __syncthreads();
  }
  if (t < NBLK1) part[t] = l[t] - v;
}

__global__ void k_scan3(int* off, const int* __restrict__ part){
  int i = blockIdx.x*blockDim.x + threadIdx.x;
  if (i < NN) off[i] += part[i >> 10];
  if (i == 0) off[NN] = NE;
}

__global__ void k_fill(const int* __restrict__ src, const int* __restrict__ dst,
                       const int* __restrict__ off, int* cur, int* __restrict__ csr){
  int e = blockIdx.x*blockDim.x + threadIdx.x;
  if (e < NE){
    int d = dst[e];
    int p = atomicAdd(&cur[d], 1);
    csr[off[d] + p] = src[e];
  }
}

// ---------------- dense linears: 8 rows/wave, W columns in VGPRs ----------------
// x rows staged in wave-private LDS (no barrier); reads back are lane-uniform
// broadcasts (cheap); weight chunk held in 32 VGPRs, loaded from global (L1-hit).

// hs[N,64] = (x[N,128] @ w[128,64]) * dinv[row]
__global__ __launch_bounds__(256) void k_gemm_in(const float* __restrict__ x,
                                                 const float* __restrict__ w,
                                                 const float* __restrict__ dinv,
                                                 float* __restrict__ hs){
  __shared__ float xl[4][8][INF_];
  const int wave = threadIdx.x >> 6, lane = threadIdx.x & 63;
  int rb = blockIdx.x*32 + wave*8;
  if (rb >= NN) return;
  #pragma unroll
  for (int r = 0; r < 8; ++r){
    xl[wave][r][lane]      = x[(size_t)(rb+r)*INF_ + lane];
    xl[wave][r][lane + 64] = x[(size_t)(rb+r)*INF_ + lane + 64];
  }
  float acc[8] = {0.f,0.f,0.f,0.f,0.f,0.f,0.f,0.f};
  #pragma unroll
  for (int c = 0; c < 4; ++c){
    float wv[32];
    #pragma unroll
    for (int j = 0; j < 32; ++j) wv[j] = w[(c*32 + j)*HID + lane];
    #pragma unroll
    for (int r = 0; r < 8; ++r)
      #pragma unroll
      for (int j = 0; j < 32; ++j)
        acc[r] = fmaf(xl[wave][r][c*32 + j], wv[j], acc[r]);
  }
  #pragma unroll
  for (int r = 0; r < 8; ++r)
    hs[(size_t)(rb+r)*HID + lane] = acc[r]*dinv[rb+r];
}

// h2pre = h1 @ gat_w; as_ = h2pre.att_src; ad_ = h2pre.att_dst
__global__ __launch_bounds__(256) void k_gat_lin(const float* __restrict__ h1,
                                                 const float* __restrict__ w,
                                                 const float* __restrict__ atts,
                                                 const float* __restrict__ attd,
                                                 float* __restrict__ h2pre,
                                                 float* __restrict__ as_,
                                                 float* __restrict__ ad_){
  __shared__ float xl[4][8][HID];
  const int wave = threadIdx.x >> 6, lane = threadIdx.x & 63;
  int rb = blockIdx.x*32 + wave*8;
  if (rb >= NN) return;
  float as_l = atts[lane], ad_l = attd[lane];
  #pragma unroll
  for (int r = 0; r < 8; ++r)
    xl[wave][r][lane] = h1[(size_t)(rb+r)*HID + lane];
  float acc[8] = {0.f,0.f,0.f,0.f,0.f,0.f,0.f,0.f};
  #pragma unroll
  for (int c = 0; c < 2; ++c){
    float wv[32];
    #pragma unroll
    for (int j = 0; j < 32; ++j) wv[j] = w[(c*32 + j)*HID + lane];
    #pragma unroll
    for (int r = 0; r < 8; ++r)
      #pragma unroll
      for (int j = 0; j < 32; ++j)
        acc[r] = fmaf(xl[wave][r][c*32 + j], wv[j], acc[r]);
  }
  #pragma unroll
  for (int r = 0; r < 8; ++r){
    h2pre[(size_t)(rb+r)*HID + lane] = acc[r];
    float vs = acc[r]*as_l, vd = acc[r]*ad_l;
    #pragma unroll
    for (int o = 32; o > 0; o >>= 1){
      vs += __shfl_xor(vs, o, 64);
      vd += __shfl_xor(vd, o, 64);
    }
    if (lane == 0){ as_[rb+r] = vs; ad_[rb+r] = vd; }
  }
}

// out = mean@wl + h2@wr + b   (mean/out may alias; row-block local RAW is safe)
__global__ __launch_bounds__(256) void k_sage_dense(const float* mean,
                                                    const float* __restrict__ h2,
                                                    const float* __restrict__ wlh,
                                                    const float* __restrict__ wrh,
                                                    const float* __restrict__ b,
                                                    float* out){
  __shared__ float ml[4][8][HID];
  __shared__ float hl[4][8][HID];
  const int wave = threadIdx.x >> 6, lane = threadIdx.x & 63;
  int rb = blockIdx.x*32 + wave*8;
  if (rb >= NN) return;
  float bl = b[lane];
  #pragma unroll
  for (int r = 0; r < 8; ++r){
    ml[wave][r][lane] = mean[(size_t)(rb+r)*HID + lane];
    hl[wave][r][lane] = h2[(size_t)(rb+r)*HID + lane];
  }
  float acc[8] = {bl,bl,bl,bl,bl,bl,bl,bl};
  #pragma unroll
  for (int c = 0; c < 2; ++c){
    float wvl[32], wvr[32];
    #pragma unroll
    for (int j = 0; j < 32; ++j){
      wvl[j] = wlh[(c*32 + j)*HID + lane];
      wvr[j] = wrh[(c*32 + j)*HID + lane];
    }
    #pragma unroll
    for (int r = 0; r < 8; ++r)
      #pragma unroll
      for (int j = 0; j < 32; ++j){
        acc[r] = fmaf(ml[wave][r][c*32 + j], wvl[j], acc[r]);
        acc[r] = fmaf(hl[wave][r][c*32 + j], wvr[j], acc[r]);
      }
  }
  #pragma unroll
  for (int r = 0; r < 8; ++r)
    out[(size_t)(rb+r)*HID + lane] = acc[r];
}

// ---------------- gather aggregations: 4-row-slot x float4, 16 rows in flight ----

// GCN: h1 = relu((sum_s hs[s] + hs[i]) * dinv[i] + gcn_b)
__global__ __launch_bounds__(256) void k_gcn_gather(const int* __restrict__ csr,
                                                    const int* __restrict__ off,
                                                    const float4* __restrict__ hs4,
                                                    const float* __restrict__ dinv,
                                                    const float4* __restrict__ gcn_b4,
                                                    float4* __restrict__ h1_4){
  int node = blockIdx.x*4 + (threadIdx.x >> 6);
  if (node >= NN) return;
  int lane = threadIdx.x & 63;
  int q = lane >> 4, f = lane & 15;
  int beg = off[node], end = off[node+1];
  float4 acc = {0.f,0.f,0.f,0.f};
  for (int c = beg; c < end; c += 64){
    int n = end - c; if (n > 64) n = 64;
    int idx = (lane < n) ? csr[c + lane] : 0;
    for (int k = 0; k < n; k += 16){
      int e0 = k + q, e1 = k + 4 + q, e2 = k + 8 + q, e3 = k + 12 + q;
      int s0 = __shfl(idx, e0, 64);
      int s1 = __shfl(idx, e1, 64);
      int s2 = __shfl(idx, e2, 64);
      int s3 = __shfl(idx, e3, 64);
      if (e0 < n){ float4 r = hs4[(size_t)s0*16 + f]; acc.x+=r.x; acc.y+=r.y; acc.z+=r.z; acc.w+=r.w; }
      if (e1 < n){ float4 r = hs4[(size_t)s1*16 + f]; acc.x+=r.x; acc.y+=r.y; acc.z+=r.z; acc.w+=r.w; }
      if (e2 < n){ float4 r = hs4[(size_t)s2*16 + f]; acc.x+=r.x; acc.y+=r.y; acc.z+=r.z; acc.w+=r.w; }
      if (e3 < n){ float4 r = hs4[(size_t)s3*16 + f]; acc.x+=r.x; acc.y+=r.y; acc.z+=r.z; acc.w+=r.w; }
    }
  }
  #pragma unroll
  for (int o = 16; o <= 32; o <<= 1){
    acc.x += __shfl_xor(acc.x, o, 64);
    acc.y += __shfl_xor(acc.y, o, 64);
    acc.z += __shfl_xor(acc.z, o, 64);
    acc.w += __shfl_xor(acc.w, o, 64);
  }
  if (q == 0){
    float4 s  = hs4[(size_t)node*16 + f];
    float  di = dinv[node];
    float4 b4 = gcn_b4[f];
    float4 o;
    o.x = fmaxf((acc.x + s.x)*di + b4.x, 0.f);
    o.y = fmaxf((acc.y + s.y)*di + b4.y, 0.f);
    o.z = fmaxf((acc.z + s.z)*di + b4.z, 0.f);
    o.w = fmaxf((acc.w + s.w)*di + b4.w, 0.f);
    h1_4[(size_t)node*16 + f] = o;
  }
}

// GAT: fused segment softmax + weighted gather
__global__ __launch_bounds__(256) void k_gat_gather(const int* __restrict__ csr,
                                                    const int* __restrict__ off,
                                                    const float* __restrict__ as_,
                                                    const float* __restrict__ ad_,
                                                    const float4* __restrict__ h2pre4,
                                                    const float4* __restrict__ gat_b4,
                                                    float4* __restrict__ h2_4){
  int node = blockIdx.x*4 + (threadIdx.x >> 6);
  if (node >= NN) return;
  int lane = threadIdx.x & 63;
  int q = lane >> 4, f = lane & 15;
  int beg = off[node], end = off[node+1];
  float adi = ad_[node];
  float eself = lrelu(as_[node] + adi);
  float lm = -1e30f;
  for (int c = beg + lane; c < end; c += 64)
    lm = fmaxf(lm, lrelu(as_[csr[c]] + adi));
  #pragma unroll
  for (int o = 32; o > 0; o >>= 1) lm = fmaxf(lm, __shfl_xor(lm, o, 64));
  float m = fmaxf(eself, lm);
  float ps = expf(eself - m);
  float ssum = 0.f;
  float4 acc = {0.f,0.f,0.f,0.f};
  for (int c = beg; c < end; c += 64){
    int n = end - c; if (n > 64) n = 64;
    int idx = 0; float pv = 0.f;
    if (lane < n){
      idx = csr[c + lane];
      pv = expf(lrelu(as_[idx] + adi) - m);
    }
    for (int k = 0; k < n; k += 16){
      int e0 = k + q, e1 = k + 4 + q, e2 = k + 8 + q, e3 = k + 12 + q;
      int s0 = __shfl(idx, e0, 64); float p0 = __shfl(pv, e0, 64);
      int s1 = __shfl(idx, e1, 64); float p1 = __shfl(pv, e1, 64);
      int s2 = __shfl(idx, e2, 64); float p2 = __shfl(pv, e2, 64);
      int s3 = __shfl(idx, e3, 64); float p3 = __shfl(pv, e3, 64);
      if (e0 < n){ float4 r = h2pre4[(size_t)s0*16 + f]; acc.x+=r.x*p0; acc.y+=r.y*p0; acc.z+=r.z*p0; acc.w+=r.w*p0; ssum += p0; }
      if (e1 < n){ float4 r = h2pre4[(size_t)s1*16 + f]; acc.x+=r.x*p1; acc.y+=r.y*p1; acc.z+=r.z*p1; acc.w+=r.w*p1; ssum += p1; }
      if (e2 < n){ float4 r = h2pre4[(size_t)s2*16 + f]; acc.x+=r.x*p2; acc.y+=r.y*p2; acc.z+=r.z*p2; acc.w+=r.w*p2; ssum += p2; }
      if (e3 < n){ float4 r = h2pre4[(size_t)s3*16 + f]; acc.x+=r.x*p3; acc.y+=r.y*p3; acc.z+=r.z*p3; acc.w+=r.w*p3; ssum += p3; }
    }
  }
  #pragma unroll
  for (int o = 16; o <= 32; o <<= 1){
    acc.x += __shfl_xor(acc.x, o, 64);
    acc.y += __shfl_xor(acc.y, o, 64);
    acc.z += __shfl_xor(acc.z, o, 64);
    acc.w += __shfl_xor(acc.w, o, 64);
    ssum  += __shfl_xor(ssum,  o, 64);
  }
  if (q == 0){
    float inv = 1.f/(ssum + ps);
    float4 h0 = h2pre4[(size_t)node*16 + f];
    float4 b4 = gat_b4[f];
    float4 o;
    o.x = fmaxf((acc.x + h0.x*ps)*inv + b4.x, 0.f);
    o.y = fmaxf((acc.y + h0.y*ps)*inv + b4.y, 0.f);
    o.z = fmaxf((acc.z + h0.z*ps)*inv + b4.z, 0.f);
    o.w = fmaxf((acc.w + h0.w*ps)*inv + b4.w, 0.f);
    h2_4[(size_t)node*16 + f] = o;
  }
}

// SAGE gather: mean of h2 rows over incoming edges
__global__ __launch_bounds__(256) void k_sage_gather(const int* __restrict__ csr,
                                                     const int* __restrict__ off,
                                                     const int* __restrict__ cnt,
                                                     const float4* __restrict__ h2_4,
                                                     float4* __restrict__ mean4){
  int node = blockIdx.x*4 + (threadIdx.x >> 6);
  if (node >= NN) return;
  int lane = threadIdx.x & 63;
  int q = lane >> 4, f = lane & 15;
  int beg = off[node], end = off[node+1];
  float4 acc = {0.f,0.f,0.f,0.f};
  for (int c = beg; c < end; c += 64){
    int n = end - c; if (n > 64) n = 64;
    int idx = (lane < n) ? csr[c + lane] : 0;
    for (int k = 0; k < n; k += 16){
      int e0 = k + q, e1 = k + 4 + q, e2 = k + 8 + q, e3 = k + 12 + q;
      int s0 = __shfl(idx, e0, 64);
      int s1 = __shfl(idx, e1, 64);
      int s2 = __shfl(idx, e2, 64);
      int s3 = __shfl(idx, e3, 64);
      if (e0 < n){ float4 r = h2_4[(size_t)s0*16 + f]; acc.x+=r.x; acc.y+=r.y; acc.z+=r.z; acc.w+=r.w; }
      if (e1 < n){ float4 r = h2_4[(size_t)s1*16 + f]; acc.x+=r.x; acc.y+=r.y; acc.z+=r.z; acc.w+=r.w; }
      if (e2 < n){ float4 r = h2_4[(size_t)s2*16 + f]; acc.x+=r.x; acc.y+=r.y; acc.z+=r.z; acc.w+=r.w; }
      if (e3 < n){ float4 r = h2_4[(size_t)s3*16 + f]; acc.x+=r.x; acc.y+=r.y; acc.z+=r.z; acc.w+=r.w; }
    }
  }
  #pragma unroll
  for (int o = 16; o <= 32; o <<= 1){
    acc.x += __shfl_xor(acc.x, o, 64);
    acc.y += __shfl_xor(acc.y, o, 64);
    acc.z += __shfl_xor(acc.z, o, 64);
    acc.w += __shfl_xor(acc.w, o, 64);
  }
  if (q == 0){
    float inv = 1.f/fmaxf((float)cnt[node], 1.f);
    float4 o = {acc.x*inv, acc.y*inv, acc.z*inv, acc.w*inv};
    mean4[(size_t)node*16 + f] = o;
  }
}

// ---------------- launch ----------------

extern "C" void kernel_launch(void* const* d_in, const int* in_sizes, int n_in,
                              void* d_out, int out_size, void* d_ws, size_t ws_size,
                              hipStream_t stream) {
  const float* x      = (const float*)d_in[0];
  const int*   ei     = (const int*)d_in[1];
  const int*   src    = ei;
  const int*   dstp   = ei + NE;
  const float* gcn_w  = (const float*)d_in[2];
  const float* gcn_b  = (const float*)d_in[3];
  const float* gat_w  = (const float*)d_in[4];
  const float* att_s  = (const float*)d_in[5];
  const float* att_d  = (const float*)d_in[6];
  const float* gat_b  = (const float*)d_in[7];
  const float* s_wl   = (const float*)d_in[8];
  const float* s_wr   = (const float*)d_in[9];
  const float* s_b    = (const float*)d_in[10];
  float* outp = (float*)d_out;

  // workspace layout (4-byte words)
  int*   cnt  = (int*)d_ws;          // N
  int*   cur  = cnt + NN;            // N
  int*   off  = cur + NN;            // N+1
  int*   part = off + NN + 1;        // 1024 (pad)
  float* dinv = (float*)(part + 1024);
  float* as_  = dinv + NN;
  float* ad_  = as_  + NN;
  int*   csr  = (int*)(ad_ + NN);    // NE
  float* BIG0 = (float*)(csr + NE);  // N*HID
  float* BIG1 = BIG0 + (size_t)NN*HID;

  size_t need_full = ((size_t)5*NN + 1 + 1024 + NE + (size_t)2*NN*HID)*4;
  float *P_hs, *P_h1, *P_h2pre, *P_h2, *P_mean;
  if (ws_size >= need_full){
    P_hs = BIG0; P_h1 = BIG1; P_h2pre = outp; P_h2 = BIG1; P_mean = BIG0;
  } else {
    P_hs = outp; P_h1 = BIG0; P_h2pre = outp; P_h2 = BIG0; P_mean = outp;
  }

  const int B = 256;
  const int GROWS = (NN + 31)/32;    // 3125 blocks, 8 rows/wave
  // CSR build (counting sort by dst)
  k_zero_i<<<(2*NN + B-1)/B, B, 0, stream>>>(cnt, 2*NN);
  k_count <<<(NE + B-1)/B, B, 0, stream>>>(dstp, cnt);
  k_dinv  <<<(NN + B-1)/B, B, 0, stream>>>(cnt, dinv);
  k_scan1 <<<NBLK1, B, 0, stream>>>(cnt, off, part);
  k_scan2 <<<1, 128, 0, stream>>>(part);
  k_scan3 <<<(NN + B-1)/B, B, 0, stream>>>(off, part);
  k_fill  <<<(NE + B-1)/B, B, 0, stream>>>(src, dstp, off, cur, csr);

  // GCN
  k_gemm_in   <<<GROWS, B, 0, stream>>>(x, gcn_w, dinv, P_hs);
  k_gcn_gather<<<(NN + 3)/4, B, 0, stream>>>(csr, off, (const float4*)P_hs, dinv,
                                             (const float4*)gcn_b, (float4*)P_h1);

  // GAT
  k_gat_lin   <<<GROWS, B, 0, stream>>>(P_h1, gat_w, att_s, att_d, P_h2pre, as_, ad_);
  k_gat_gather<<<(NN + 3)/4, B, 0, stream>>>(csr, off, as_, ad_, (const float4*)P_h2pre,
                                             (const float4*)gat_b, (float4*)P_h2);

  // SAGE
  k_sage_gather<<<(NN + 3)/4, B, 0, stream>>>(csr, off, cnt, (const float4*)P_h2,
                                              (float4*)P_mean);
  k_sage_dense <<<GROWS, B, 0, stream>>>(P_mean, P_h2, s_wl, s_wr, s_b, outp);
}